// Round 2
// baseline (319.608 us; speedup 1.0000x reference)
//
#include <hip/hip_runtime.h>
#include <math.h>

#define BS 131072
#define L 128
#define NCH 10
#define EMB 256
#define ZD 128
#define KCB 64
#define NF 290
#define RPB 64    // rows per block
#define TPB 128   // 2 waves

#define FP 296    // feat pitch (elems): 290 feats + 6 zero pad; 592B rows (16B mult)
#define PP 164    // pr-stage pitch (elems): 128 + 36 zero pad; 328B rows (8B mult)

typedef __attribute__((ext_vector_type(8))) short short8;   // 8 bf16 = 4 VGPRs
typedef __attribute__((ext_vector_type(4))) short short4v;  // 4 bf16 = 2 VGPRs
typedef __attribute__((ext_vector_type(4))) float float4v;  // MFMA C/D

// ---- workspace float-offsets
#define WS_BC    0                    // combined bias [128]
#define WS_CNORM 128                  // ||code||^2 [64]
#define WS_CBT   192                  // codebook^T [128][64]
#define WS_CNT   8384                 // int counts [64]
#define WS_ESUM  8448                 // float e_sum
#define WS_WHI   8452                 // W_hi frags: 40960 bf16 (20480 floats), 16B-aligned
#define WS_WLO   28932                // W_lo frags: 40960 bf16

static __device__ __forceinline__ short f2bf(float x) {  // RNE fp32->bf16
  unsigned u = __float_as_uint(x);
  return (short)((u + 0x7fffu + ((u >> 16) & 1u)) >> 16);
}
static __device__ __forceinline__ float bf2f(short s) {
  return __uint_as_float(((unsigned)(unsigned short)s) << 16);
}
static __device__ __forceinline__ short8 ld_b64x2(const short* p) {
  short4v a = *(const short4v*)p;
  short4v b = *(const short4v*)(p + 4);
  short8 r;
  r[0]=a[0]; r[1]=a[1]; r[2]=a[2]; r[3]=a[3];
  r[4]=b[0]; r[5]=b[1]; r[6]=b[2]; r[7]=b[3];
  return r;
}

// ---------------- prep: fused W in B-fragment hi/lo layout, bias, cnorm, cbT, zeros
// Fragment tensor layout [kstep10][nt8][lane64][j8]; global K index f = ks*32 + (lane>>4)*8 + j,
// valid for f < 290 (natural f = ch*29 + jpool ordering). One block per (ks,nt) tile: b = ks*8+nt.
__global__ void k_prep(const float* __restrict__ fc_w, const float* __restrict__ fc_b,
                       const float* __restrict__ mu_w, const float* __restrict__ mu_b,
                       const float* __restrict__ codebook, float* __restrict__ ws) {
  const int b = blockIdx.x, t = threadIdx.x;
  if (b < 80) {
    __shared__ float fcT[32 * 260];   // [kk][e]
    __shared__ float mus[16 * 260];   // [zz][e]
    const int ks = b >> 3, nt = b & 7;
    const int f0 = ks * 32;
    const int nval = (290 - f0 < 32) ? (290 - f0) : 32;

    // stage fc columns (transposed), zero for invalid f (>=290)
    {
      const int kk = t & 31, esub = t >> 5;
      const bool valid = kk < nval;
#pragma unroll
      for (int p = 0; p < 32; ++p) {
        int e = p * 8 + esub;
        fcT[kk * 260 + e] = valid ? fc_w[e * NF + f0 + kk] : 0.0f;
      }
    }
    // stage mu rows as float4
    {
#pragma unroll
      for (int p = 0; p < 4; ++p) {
        int idx = p * 256 + t;
        int zz = idx >> 6, e4 = idx & 63;
        *(float4*)&mus[zz * 260 + e4 * 4] =
            *(const float4*)&mu_w[(nt * 16 + zz) * EMB + e4 * 4];
      }
    }
    __syncthreads();

    // thread t -> outputs (lane=lane_lo, j) and (lane=lane_lo+32, j); same z.
    const int lane_lo = t >> 3, j = t & 7;
    const int z = lane_lo & 15;
    const int kka = ((lane_lo >> 4) & 1) * 8 + j;       // k local 0..15
    const int kkb = kka + 16;                           // k local 16..31
    float a0 = 0, a1 = 0, a2 = 0, a3 = 0, b0 = 0, b1 = 0, b2 = 0, b3 = 0;
#pragma unroll 8
    for (int e = 0; e < 256; e += 4) {
      float4 m  = *(const float4*)&mus[z * 260 + e];
      float4 fa = *(const float4*)&fcT[kka * 260 + e];
      float4 fb = *(const float4*)&fcT[kkb * 260 + e];
      a0 = fmaf(m.x, fa.x, a0); a1 = fmaf(m.y, fa.y, a1);
      a2 = fmaf(m.z, fa.z, a2); a3 = fmaf(m.w, fa.w, a3);
      b0 = fmaf(m.x, fb.x, b0); b1 = fmaf(m.y, fb.y, b1);
      b2 = fmaf(m.z, fb.z, b2); b3 = fmaf(m.w, fb.w, b3);
    }
    float va = (a0 + a1) + (a2 + a3);
    float vb = (b0 + b1) + (b2 + b3);
    short* hi = (short*)(ws + WS_WHI);
    short* lo = (short*)(ws + WS_WLO);
    const int base = b * 512;
    short ha = f2bf(va); short la = f2bf(va - bf2f(ha));
    short hb = f2bf(vb); short lb = f2bf(vb - bf2f(hb));
    hi[base + t] = ha;        lo[base + t] = la;
    hi[base + 256 + t] = hb;  lo[base + 256 + t] = lb;
  } else if (b == 80) {
    if (t < ZD) {
      float p0 = 0, p1 = 0, p2 = 0, p3 = 0;
      const float* mw = mu_w + (size_t)t * EMB;
      for (int e = 0; e < EMB; e += 4) {
        p0 = fmaf(mw[e + 0], fc_b[e + 0], p0);
        p1 = fmaf(mw[e + 1], fc_b[e + 1], p1);
        p2 = fmaf(mw[e + 2], fc_b[e + 2], p2);
        p3 = fmaf(mw[e + 3], fc_b[e + 3], p3);
      }
      ws[WS_BC + t] = mu_b[t] + ((p0 + p1) + (p2 + p3));
    }
  } else if (b == 81) {
    if (t < KCB) {
      double acc = 0.0;
      for (int k = 0; k < ZD; ++k) { double v = (double)codebook[t * ZD + k]; acc += v * v; }
      ws[WS_CNORM + t] = (float)acc;
    } else if (t < 128) {
      ((int*)ws)[WS_CNT + (t - 64)] = 0;
    } else if (t == 128) {
      ws[WS_ESUM] = 0.0f;
    }
  } else {  // b == 82: codebook transpose -> [k][code]
    for (int i = 0; i < 32; ++i) {
      int idx = i * 256 + t;
      int k = idx >> 6, cc = idx & 63;
      ws[WS_CBT + idx] = codebook[cc * ZD + k];
    }
  }
}

// ---------------- fused main: MFMA conv+pool -> MFMA GEMM (per 16-row group) -> VQ -> z
// LDS raw (33024 B) layout during compute phases (all dead before mu_s alias):
//   feat_hi [16][296] @ 0       (9472 B)
//   feat_lo [16][296] @ 9472    (9472 B)
//   prs_hi  [16][164] @ 18944   (5248 B)
//   prs_lo  [16][164] @ 24192   (5248 B)  -> end 29440 < 33024
__launch_bounds__(TPB, 2)
__global__ void k_main(const float* __restrict__ pr, const int* __restrict__ mask,
                       const float* __restrict__ conv_w, const float* __restrict__ conv_b,
                       const float* __restrict__ codebook,
                       float* __restrict__ ws, float* __restrict__ out) {
  __shared__ __align__(16) unsigned char lds_raw[33024];
  __shared__ float aux_val[RPB * 8];
  __shared__ int   aux_idx[RPB * 8];
  __shared__ int   bi_s[RPB];
  __shared__ float validf[RPB];
  __shared__ int   hist[KCB];

  short* feat_hi = (short*)lds_raw;
  short* feat_lo = (short*)(lds_raw + 9472);
  short* prs_hi  = (short*)(lds_raw + 18944);
  short* prs_lo  = (short*)(lds_raw + 24192);
  float* mu_s    = (float*)lds_raw;            // [64][129] fp32, aliases after GEMM

  const int tid = threadIdx.x;
  const int lane = tid & 63, wv = tid >> 6;
  const int q4 = lane >> 4, c16 = lane & 15;
  const long rowg0 = (long)blockIdx.x * RPB;

  if (tid < KCB) hist[tid] = 0;
  // zero pads ONCE (persist across row-groups; conv/staging never write them):
  // feat cols 290..295 (hi+lo) and prs cols 128..163 (hi+lo)
  for (int i = tid; i < 16 * 6; i += TPB) {
    int r = i / 6, kk = 290 + (i % 6);
    feat_hi[r * FP + kk] = 0;
    feat_lo[r * FP + kk] = 0;
  }
  for (int i = tid; i < 16 * 36; i += TPB) {
    int r = i / 36, kk = 128 + (i % 36);
    prs_hi[r * PP + kk] = 0;
    prs_lo[r * PP + kk] = 0;
  }

  // ---- conv-weight MFMA A-fragments (m=(ch,d), k=v; W_d[v]=w[v-d], zero for v>=16), hi/lo
  short8 cwh[3], cwl[3];
  {
    const int chl = c16 >> 2, d = c16 & 3;
#pragma unroll
    for (int cg = 0; cg < 3; ++cg) {
      const int ch = cg * 4 + chl;
#pragma unroll
      for (int e = 0; e < 8; ++e) {
        int v = q4 * 8 + e, u = v - d;
        float val = (ch < NCH && u >= 0 && u < 12) ? conv_w[ch * 12 + u] : 0.0f;
        short h = f2bf(val);
        cwh[cg][e] = h;
        cwl[cg][e] = f2bf(val - bf2f(h));
      }
    }
  }
  float cb[3];
#pragma unroll
  for (int cg = 0; cg < 3; ++cg) {
    int ch = cg * 4 + q4;
    cb[cg] = (ch < NCH) ? conv_b[ch] : 0.0f;
  }

  // accumulators [rowgroup][ntile_local], init with fused FC bias (broadcast per C-col)
  const float* bc = ws + WS_BC;
  float4v acc[4][4];
#pragma unroll
  for (int ntl = 0; ntl < 4; ++ntl) {
    float bv = bc[wv * 64 + ntl * 16 + c16];
    float4v b4 = {bv, bv, bv, bv};
#pragma unroll
    for (int rg = 0; rg < 4; ++rg) acc[rg][ntl] = b4;
  }

  const short* whi = (const short*)(ws + WS_WHI);
  const short* wlo = (const short*)(ws + WS_WLO);

  const int jlo = wv * 15;              // wave0: j 0..14, wave1: j 15..28
  const int jhi = wv ? 29 : 15;
  const int srow = tid >> 3, sseg = tid & 7;   // pr staging: 8 threads/row, 16 floats each

#pragma unroll
  for (int rg = 0; rg < 4; ++rg) {
    // ---- stage 16 rows of pr -> bf16 hi/lo in LDS
    {
      const float* pg = pr + (rowg0 + rg * 16 + srow) * (long)L + sseg * 16;
      short* ph = prs_hi + srow * PP + sseg * 16;
      short* pl = prs_lo + srow * PP + sseg * 16;
#pragma unroll
      for (int i = 0; i < 4; ++i) {
        float4 v = *(const float4*)(pg + i * 4);
        short h0 = f2bf(v.x), h1 = f2bf(v.y), h2 = f2bf(v.z), h3 = f2bf(v.w);
        short4v hv = {h0, h1, h2, h3};
        short4v lv = {f2bf(v.x - bf2f(h0)), f2bf(v.y - bf2f(h1)),
                      f2bf(v.z - bf2f(h2)), f2bf(v.w - bf2f(h3))};
        *(short4v*)(ph + i * 4) = hv;
        *(short4v*)(pl + i * 4) = lv;
      }
    }
    __syncthreads();

    // ---- conv+pool via MFMA: D[(ch,d)][r] = sum_v W_d[v]*pr[r][4j+v], per pooled j
#pragma unroll 1
    for (int j = jlo; j < jhi; ++j) {
      const int po = c16 * PP + 4 * j + 8 * q4;   // B-frag: lane n=r=c16, k=8*q4+e
      short8 bh = ld_b64x2(prs_hi + po);
      short8 bl = ld_b64x2(prs_lo + po);
#pragma unroll
      for (int cg = 0; cg < 3; ++cg) {
        float bv = cb[cg];
        float4v c = {bv, bv, bv, bv};
        c = __builtin_amdgcn_mfma_f32_16x16x32_bf16(cwh[cg], bh, c, 0, 0, 0);
        c = __builtin_amdgcn_mfma_f32_16x16x32_bf16(cwh[cg], bl, c, 0, 0, 0);
        c = __builtin_amdgcn_mfma_f32_16x16x32_bf16(cwl[cg], bh, c, 0, 0, 0);
        // D rows for this lane: ch = q4, d = reg -> pool over own regs, no shuffles
        if (cg < 2 || q4 < 2) {
          float m = fmaxf(fmaxf(c[0], c[1]), fmaxf(c[2], c[3]));
          m = fmaxf(m, 0.0f);                     // relu(max) == max(relu)
          int kl = (cg * 4 + q4) * 29 + j;
          short h = f2bf(m);
          feat_hi[c16 * FP + kl] = h;
          feat_lo[c16 * FP + kl] = f2bf(m - bf2f(h));
        }
      }
    }
    __syncthreads();

    // ---- GEMM for this row-group: K=320 (10 ksteps), split-bf16 (3 MFMAs)
#pragma unroll 2
    for (int g = 0; g < 10; ++g) {
      const int ao = c16 * FP + g * 32 + q4 * 8;  // A-frag: m=c16 (local row), k=q4*8+e
      short8 ah = *(const short8*)(feat_hi + ao); // overreads at k>=290 hit finite LDS data,
      short8 al = *(const short8*)(feat_lo + ao); // W-frags are exactly 0 there -> contributes 0
#pragma unroll
      for (int ntl = 0; ntl < 4; ++ntl) {
        int nt = wv * 4 + ntl;
        int fo = ((g * 8 + nt) * 64 + lane) * 8;
        short8 bh = *(const short8*)(whi + fo);
        short8 bl = *(const short8*)(wlo + fo);
        acc[rg][ntl] = __builtin_amdgcn_mfma_f32_16x16x32_bf16(ah, bh, acc[rg][ntl], 0, 0, 0);
        acc[rg][ntl] = __builtin_amdgcn_mfma_f32_16x16x32_bf16(ah, bl, acc[rg][ntl], 0, 0, 0);
        acc[rg][ntl] = __builtin_amdgcn_mfma_f32_16x16x32_bf16(al, bh, acc[rg][ntl], 0, 0, 0);
      }
    }
    __syncthreads();   // protects prs/feat rewrite next rg AND mu_s alias after loop
  }

  // ---- C-layout store to mu_s: row = rg*16 + q4*4 + r, col = wv*64 + ntl*16 + c16
#pragma unroll
  for (int rg = 0; rg < 4; ++rg)
#pragma unroll
    for (int ntl = 0; ntl < 4; ++ntl) {
      int col = wv * 64 + ntl * 16 + c16;
      int rowb = rg * 16 + q4 * 4;
#pragma unroll
      for (int r = 0; r < 4; ++r)
        mu_s[(rowb + r) * 129 + col] = acc[rg][ntl][r];
    }
  __syncthreads();

  // ---- VQ distances: thread tile 4 rows x 8 codes (fp32 exact)
  const float* cnorm = ws + WS_CNORM;
  const float* cbT   = ws + WS_CBT;
  const int tvr = tid & 15, tvc = tid >> 4;
  const int rv0 = tvr * 4, cbo = tvc * 8;
  float s[4][8];
#pragma unroll
  for (int i = 0; i < 4; ++i)
#pragma unroll
    for (int j = 0; j < 8; ++j) s[i][j] = 0.0f;
#pragma unroll 4
  for (int k = 0; k < 128; ++k) {
    float m0 = mu_s[(rv0 + 0) * 129 + k];
    float m1 = mu_s[(rv0 + 1) * 129 + k];
    float m2 = mu_s[(rv0 + 2) * 129 + k];
    float m3 = mu_s[(rv0 + 3) * 129 + k];
    float4 ca = *(const float4*)&cbT[k * 64 + cbo];
    float4 cb4 = *(const float4*)&cbT[k * 64 + cbo + 4];
    float cv[8] = {ca.x, ca.y, ca.z, ca.w, cb4.x, cb4.y, cb4.z, cb4.w};
    float mv[4] = {m0, m1, m2, m3};
#pragma unroll
    for (int i = 0; i < 4; ++i)
#pragma unroll
      for (int j = 0; j < 8; ++j) s[i][j] = fmaf(mv[i], cv[j], s[i][j]);
  }
  {
    float4 n0 = *(const float4*)&cnorm[cbo];
    float4 n1 = *(const float4*)&cnorm[cbo + 4];
    float nv[8] = {n0.x, n0.y, n0.z, n0.w, n1.x, n1.y, n1.z, n1.w};
#pragma unroll
    for (int i = 0; i < 4; ++i) {
      float best = nv[0] - 2.0f * s[i][0];
      int bi = cbo;
#pragma unroll
      for (int j = 1; j < 8; ++j) {
        float d = nv[j] - 2.0f * s[i][j];
        if (d < best) { best = d; bi = cbo + j; }
      }
      aux_val[(rv0 + i) * 8 + tvc] = best;
      aux_idx[(rv0 + i) * 8 + tvc] = bi;
    }
  }
  __syncthreads();

  if (tid < RPB) {
    float best = aux_val[tid * 8];
    int bi = aux_idx[tid * 8];
#pragma unroll
    for (int v = 1; v < 8; ++v) {
      float x = aux_val[tid * 8 + v];
      if (x < best) { best = x; bi = aux_idx[tid * 8 + v]; }
    }
    bi_s[tid] = bi;
    validf[tid] = (mask[rowg0 + tid] == 0) ? 1.0f : 0.0f;
  }
  __syncthreads();
  if (tid < RPB) {
    if (validf[tid] > 0.5f) atomicAdd(&hist[bi_s[tid]], 1);
  }
  __syncthreads();
  if (tid < KCB && hist[tid] > 0) atomicAdd(&((int*)ws)[WS_CNT + tid], hist[tid]);

  // ---- z gather-write (coalesced) + commitment partial
  float eloc = 0.0f;
  float* zout = out + rowg0 * ZD;
#pragma unroll 2
  for (int p = 0; p < RPB; ++p) {
    int bi = bi_s[p];
    float q = codebook[bi * ZD + tid];
    float m = mu_s[p * 129 + tid];
    zout[(size_t)p * ZD + tid] = q;
    float d = q - m;
    eloc += validf[p] * d * d;
  }
#pragma unroll
  for (int o = 32; o > 0; o >>= 1) eloc += __shfl_xor(eloc, o, 64);
  if ((tid & 63) == 0) atomicAdd(&ws[WS_ESUM], eloc);
}

// ---------------- finalize scalars
__global__ void k_final(const float* __restrict__ ws, float* __restrict__ out) {
  int t = threadIdx.x;   // 64 threads
  const int* cnt = (const int*)ws + WS_CNT;
  double c = (double)cnt[t];
  double nv = c;
#pragma unroll
  for (int o = 32; o > 0; o >>= 1) nv += __shfl_xor(nv, o, 64);
  nv = fmax(nv, 1.0);
  double p = c / nv;
  double h = p * log(p + 1e-10);
#pragma unroll
  for (int o = 32; o > 0; o >>= 1) h += __shfl_xor(h, o, 64);
  if (t == 0) {
    out[(size_t)BS * ZD]     = (float)(0.25 * (double)ws[WS_ESUM] / (nv * 128.0));
    out[(size_t)BS * ZD + 1] = (float)exp(-h);
  }
}

extern "C" void kernel_launch(void* const* d_in, const int* in_sizes, int n_in,
                              void* d_out, int out_size, void* d_ws, size_t ws_size,
                              hipStream_t stream) {
  const float* pr      = (const float*)d_in[0];
  const int*   mask    = (const int*)d_in[1];
  const float* conv_w  = (const float*)d_in[2];
  const float* conv_b  = (const float*)d_in[3];
  const float* fc_w    = (const float*)d_in[4];
  const float* fc_b    = (const float*)d_in[5];
  const float* mu_w    = (const float*)d_in[6];
  const float* mu_b    = (const float*)d_in[7];
  const float* codebook= (const float*)d_in[8];
  float* ws  = (float*)d_ws;
  float* out = (float*)d_out;

  hipLaunchKernelGGL(k_prep, dim3(83), dim3(256), 0, stream,
                     fc_w, fc_b, mu_w, mu_b, codebook, ws);
  hipLaunchKernelGGL(k_main, dim3(BS / RPB), dim3(TPB), 0, stream,
                     pr, mask, conv_w, conv_b, codebook, ws, out);
  hipLaunchKernelGGL(k_final, dim3(1), dim3(64), 0, stream, ws, out);
}